// Round 9
// baseline (283.641 us; speedup 1.0000x reference)
//
#include <hip/hip_runtime.h>
#include <math.h>

#define NHEAD 4
#define HDIM 32
#define NEG_SLOPE 0.1f

typedef unsigned short u16;
typedef unsigned int u32;
typedef _Float16 f16;
typedef f16 f16x2 __attribute__((ext_vector_type(2)));
typedef f16 f16x4 __attribute__((ext_vector_type(4)));
typedef f16 f16x8 __attribute__((ext_vector_type(8)));
typedef float f32x4 __attribute__((ext_vector_type(4)));

// async 16B global->LDS (lds dest = wave-uniform base + lane*16)
#define GLLDS16(g, l) __builtin_amdgcn_global_load_lds( \
    (const __attribute__((address_space(1))) void*)(g), \
    (__attribute__((address_space(3))) void*)(l), 16, 0, 0)

// ---------------- hist + all weight-panel casts in one dispatch ----------------
// Panel layout [kt][n][kk-pair] fp16, NC cols (144 = 128 W-cols + 4 W·al + 4 W·ar + 8 zero).

__device__ __forceinline__ void cast_panel(const float* __restrict__ W,
                                           const float* __restrict__ al,
                                           const float* __restrict__ ar,
                                           u16* __restrict__ bp, int t, int NC) {
    int per_kt = NC * 16;
    int kt = t / per_kt;
    int rem = t - kt * per_kt;
    int n = rem >> 4;
    int kkp = rem & 15;
    int k = kt * 32 + kkp * 2;
    float v0 = 0.f, v1 = 0.f;
    if (n < 128) {
        v0 = W[(size_t)k * 128 + n];
        v1 = W[(size_t)(k + 1) * 128 + n];
    } else if (n < 136) {
        const float* av = (n < 132) ? al : ar;
        int h = (n < 132) ? (n - 128) : (n - 132);
        float s0 = 0.f, s1 = 0.f;
        for (int d = 0; d < 32; d++) {
            float a = av[h * 32 + d];
            s0 += W[(size_t)k * 128 + h * 32 + d] * a;
            s1 += W[(size_t)(k + 1) * 128 + h * 32 + d] * a;
        }
        v0 = s0; v1 = s1;
    }
    f16x2 p;
    p.x = (f16)v0; p.y = (f16)v1;
    *(f16x2*)&((u32*)bp)[t] = p;
}

__global__ void histcast_k(const int* __restrict__ dst, int* __restrict__ cnt, int E,
                           const float* __restrict__ W1, const float* __restrict__ al1,
                           const float* __restrict__ ar1, u16* __restrict__ b1,
                           const float* __restrict__ W2, const float* __restrict__ al2,
                           const float* __restrict__ ar2, u16* __restrict__ b2,
                           const float* __restrict__ W3, u16* __restrict__ b3) {
    int t = blockIdx.x * 256 + threadIdx.x;
    if (t < E) atomicAdd(&cnt[dst[t]], 1);
    // b1: 8 kt * 2304 = 18432 u32; b2: 4 * 2304 = 9216; b3: 8 * 2048 = 16384
    if (t < 18432) cast_panel(W1, al1, ar1, b1, t, 144);
    else if (t < 27648) cast_panel(W2, al2, ar2, b2, t - 18432, 144);
    else if (t < 44032) cast_panel(W3, nullptr, nullptr, b3, t - 27648, 128);
}

// ---------------- segment assignment: start[n] via block scan + one atomic ----------------

__global__ void assign_k(const int* __restrict__ cnt, int* __restrict__ start,
                         int* __restrict__ ctr, int N) {
    __shared__ int s[256];
    __shared__ int base;
    int t = threadIdx.x;
    int i = blockIdx.x * 256 + t;
    int v = (i < N) ? cnt[i] : 0;
    s[t] = v;
    __syncthreads();
    int incl = v;
    for (int off = 1; off < 256; off <<= 1) {
        int add = (t >= off) ? s[t - off] : 0;
        __syncthreads();
        incl += add;
        s[t] = incl;
        __syncthreads();
    }
    if (t == 255) base = atomicAdd(ctr, incl);
    __syncthreads();
    if (i < N) start[i] = base + incl - v;
}

// scatter edges into segments; (src, w) packed into one int2
__global__ void scatter_k(const int* __restrict__ src, const int* __restrict__ dst,
                          const float* __restrict__ w, const int* __restrict__ start,
                          int* __restrict__ fill, int2* __restrict__ edge_s, int E) {
    int e = blockIdx.x * 256 + threadIdx.x;
    if (e >= E) return;
    int d = dst[e];
    int p = atomicAdd(&fill[d], 1);
    edge_s[start[d] + p] = make_int2(src[e], __float_as_int(w[e]));
}

// ---------------- weight-stationary fp16 MFMA GEMM ----------------
// Full B panel (KT*NT*512 u16) preloaded in LDS; K-loop stages only A (double-buffered,
// ONE barrier/iter; the barrier drains just 256 A-chunks). Tile 64x(16*NT).
// A fp32 (reg-prefetch + cvt) or fp16 (async global->LDS). NT=9 also emits el/er.

template <int NT, int KT>
__global__ __launch_bounds__(256) void gemm_h_k(
        const void* __restrict__ Av, int a_is_f16, int lda,
        const u16* __restrict__ Bp,
        const float* __restrict__ bias, float* __restrict__ Cf,
        u16* __restrict__ Ch, float* __restrict__ el, float* __restrict__ er,
        int M) {
    __shared__ u16 Bs[KT * NT * 512];  // whole panel
    __shared__ u16 As[2][2048];        // 64 rows x 32 k, double-buffered
    int tid = threadIdx.x;
    int w = tid >> 6, lane = tid & 63;
    int row0 = blockIdx.x * 64;
    int mrow = lane & 15;
    int koff = (lane >> 4) * 8;

    const u16* Ah = (const u16*)Av;
    const float* Af = (const float*)Av;

    // preload ALL of B (linear async copy)
#pragma unroll
    for (int i = 0; i < KT * NT * 64 / 256; i++) {
        int c = tid + i * 256;
        GLLDS16(Bp + (size_t)c * 8, &Bs[c * 8]);
    }
    // stage A tile kt=0
    if (a_is_f16) {
        int c = tid;
        GLLDS16(Ah + (size_t)(row0 + (c >> 2)) * lda + ((c & 3) << 3), &As[0][c * 8]);
    } else {
#pragma unroll
        for (int i = 0; i < 2; i++) {
            int flat = tid + i * 256;
            int r = flat >> 3, c4 = flat & 7;
            int row = min(row0 + r, M - 1);  // clamp; pad rows discarded in epilogue
            float4 v = *(const float4*)&Af[(size_t)row * lda + c4 * 4];
            f16x4 p;
            p.x = (f16)v.x; p.y = (f16)v.y; p.z = (f16)v.z; p.w = (f16)v.w;
            *(f16x4*)&As[0][r * 32 + c4 * 4] = p;
        }
    }
    __syncthreads();

    f32x4 acc[NT];
#pragma unroll
    for (int nt = 0; nt < NT; nt++) acc[nt] = (f32x4){0.f, 0.f, 0.f, 0.f};

    float4 pv[2];
#pragma unroll
    for (int kt = 0; kt < KT; kt++) {
        int cur = kt & 1, nxt = cur ^ 1;
        int k0n = (kt + 1) * 32;
        if (kt + 1 < KT) {
            if (a_is_f16) {
                int c = tid;
                GLLDS16(Ah + (size_t)(row0 + (c >> 2)) * lda + k0n + ((c & 3) << 3),
                        &As[nxt][c * 8]);
            } else {
#pragma unroll
                for (int i = 0; i < 2; i++) {
                    int flat = tid + i * 256;
                    int r = flat >> 3, c4 = flat & 7;
                    int row = min(row0 + r, M - 1);
                    pv[i] = *(const float4*)&Af[(size_t)row * lda + k0n + c4 * 4];
                }
            }
        }
        f16x8 ah = *(const f16x8*)&As[cur][(w * 16 + mrow) * 32 + koff];
#pragma unroll
        for (int nt = 0; nt < NT; nt++) {
            f16x8 bh = *(const f16x8*)&Bs[(kt * NT + nt) * 512 + mrow * 32 + koff];
            acc[nt] = __builtin_amdgcn_mfma_f32_16x16x32_f16(ah, bh, acc[nt], 0, 0, 0);
        }
        if (kt + 1 < KT && !a_is_f16) {
#pragma unroll
            for (int i = 0; i < 2; i++) {
                int flat = tid + i * 256;
                int r = flat >> 3, c4 = flat & 7;
                f16x4 p;
                p.x = (f16)pv[i].x; p.y = (f16)pv[i].y;
                p.z = (f16)pv[i].z; p.w = (f16)pv[i].w;
                *(f16x4*)&As[nxt][r * 32 + c4 * 4] = p;
            }
        }
        __syncthreads();
    }

    // epilogue: C/D layout col=lane&15, row=(lane>>4)*4+reg
    int rbase = row0 + w * 16 + (lane >> 4) * 4;
#pragma unroll
    for (int nt = 0; nt < 8; nt++) {
        int col = nt * 16 + mrow;
        float bv = bias ? bias[col] : 0.f;
        f32x4 v = acc[nt];
#pragma unroll
        for (int reg = 0; reg < 4; reg++) {
            int rr = rbase + reg;
            if (rr < M) {
                float val = v[reg] + bv;
                if (Cf) Cf[(size_t)rr * 128 + col] = val;
                if (Ch) *(f16*)&Ch[(size_t)rr * 128 + col] = (f16)val;
            }
        }
    }
    if (NT == 9) {  // cols 128..135: el heads 0-3, er heads 0-3
        f32x4 v = acc[8];
#pragma unroll
        for (int reg = 0; reg < 4; reg++) {
            int rr = rbase + reg;
            if (rr < M) {
                if (mrow < 4) el[rr * 4 + mrow] = v[reg];
                else if (mrow < 8) er[rr * 4 + (mrow - 4)] = v[reg];
            }
        }
    }
}

// ---------------- fused logits + softmax + aggregation ----------------
// lane covers feature dims 2*lane, 2*lane+1; head = lane>>4. Writes fp16 into concat buffer.

__device__ __forceinline__ float lrelu(float x) {
    return x > 0.f ? x : NEG_SLOPE * x;
}

__global__ __launch_bounds__(256) void agg_k(const u32* __restrict__ fth2,
                                             const float4* __restrict__ el4,
                                             const float4* __restrict__ er4,
                                             const int2* __restrict__ edge_s,
                                             const int* __restrict__ start,
                                             const int* __restrict__ cnt,
                                             u16* __restrict__ xcat,
                                             int ooff, int N) {
    __shared__ float4 sA[256];  // [wave*64 + edge] normalized alphas
    __shared__ int sS[256];     // [wave*64 + edge] src node
    int wv = threadIdx.x >> 6;
    int n = blockIdx.x * 4 + wv;
    if (n >= N) return;
    int lane = threadIdx.x & 63;
    int head = lane >> 4;
    int r0 = start[n], deg = cnt[n];
    u16* op = &xcat[(size_t)n * 256 + ooff + 2 * lane];
    if (deg == 0) {
        *(u32*)op = 0;
        return;
    }
    float4 ern = er4[n];  // wave-uniform
    float acc0 = 0.f, acc1 = 0.f;
    if (deg <= 64) {
        // lane i owns edge i. Logits are tiny (|l| < ~2): softmax without max-shift is safe.
        float4 a = make_float4(0.f, 0.f, 0.f, 0.f);
        int s = 0;
        if (lane < deg) {
            int2 ep = edge_s[r0 + lane];
            s = ep.x;
            float we = __int_as_float(ep.y);
            float4 e = el4[s];
            a.x = __expf(we * lrelu(e.x + ern.x));
            a.y = __expf(we * lrelu(e.y + ern.y));
            a.z = __expf(we * lrelu(e.z + ern.z));
            a.w = __expf(we * lrelu(e.w + ern.w));
        }
        float4 sm = a;
        for (int m = 1; m < deg; m <<= 1) {  // truncated butterfly: lanes 0..deg-1 correct
            sm.x += __shfl_xor(sm.x, m);
            sm.y += __shfl_xor(sm.y, m);
            sm.z += __shfl_xor(sm.z, m);
            sm.w += __shfl_xor(sm.w, m);
        }
        a.x = a.x / sm.x; a.y = a.y / sm.y;
        a.z = a.z / sm.z; a.w = a.w / sm.w;
        // stage alpha/src in LDS (per-wave private; DS ops in-order within wave)
        sA[wv * 64 + lane] = a;
        sS[wv * 64 + lane] = s;
        const float* sAf = (const float*)&sA[wv * 64];
        const int* sSp = &sS[wv * 64];
        int i = 0;
        for (; i + 8 <= deg; i += 8) {  // 8 independent gathers in flight
            float wg[8];
            u32 pp[8];
#pragma unroll
            for (int j = 0; j < 8; j++) {
                wg[j] = sAf[(i + j) * 4 + head];
                pp[j] = fth2[(size_t)sSp[i + j] * 64 + lane];
            }
#pragma unroll
            for (int j = 0; j < 8; j++) {
                f16x2 hp = *(const f16x2*)&pp[j];
                acc0 += wg[j] * (float)hp.x;
                acc1 += wg[j] * (float)hp.y;
            }
        }
        for (; i < deg; i++) {
            float wgt = sAf[i * 4 + head];
            u32 p = fth2[(size_t)sSp[i] * 64 + lane];
            f16x2 hp = *(const f16x2*)&p;
            acc0 += wgt * (float)hp.x;
            acc1 += wgt * (float)hp.y;
        }
    } else {
        // fallback for deg > 64 (rare): lane-strided, keep max-shift
        float4 mx = make_float4(-INFINITY, -INFINITY, -INFINITY, -INFINITY);
        for (int i = lane; i < deg; i += 64) {
            int2 ep = edge_s[r0 + i];
            float we = __int_as_float(ep.y);
            float4 e = el4[ep.x];
            mx.x = fmaxf(mx.x, we * lrelu(e.x + ern.x));
            mx.y = fmaxf(mx.y, we * lrelu(e.y + ern.y));
            mx.z = fmaxf(mx.z, we * lrelu(e.z + ern.z));
            mx.w = fmaxf(mx.w, we * lrelu(e.w + ern.w));
        }
        for (int m = 32; m >= 1; m >>= 1) {
            mx.x = fmaxf(mx.x, __shfl_xor(mx.x, m));
            mx.y = fmaxf(mx.y, __shfl_xor(mx.y, m));
            mx.z = fmaxf(mx.z, __shfl_xor(mx.z, m));
            mx.w = fmaxf(mx.w, __shfl_xor(mx.w, m));
        }
        float4 sm = make_float4(0.f, 0.f, 0.f, 0.f);
        for (int i = lane; i < deg; i += 64) {
            int2 ep = edge_s[r0 + i];
            float we = __int_as_float(ep.y);
            float4 e = el4[ep.x];
            sm.x += __expf(we * lrelu(e.x + ern.x) - mx.x);
            sm.y += __expf(we * lrelu(e.y + ern.y) - mx.y);
            sm.z += __expf(we * lrelu(e.z + ern.z) - mx.z);
            sm.w += __expf(we * lrelu(e.w + ern.w) - mx.w);
        }
        for (int m = 32; m >= 1; m >>= 1) {
            sm.x += __shfl_xor(sm.x, m);
            sm.y += __shfl_xor(sm.y, m);
            sm.z += __shfl_xor(sm.z, m);
            sm.w += __shfl_xor(sm.w, m);
        }
        float4 inv;
        inv.x = 1.f / sm.x; inv.y = 1.f / sm.y;
        inv.z = 1.f / sm.z; inv.w = 1.f / sm.w;
        for (int i = 0; i < deg; i++) {
            int2 ep = edge_s[r0 + i];
            int si = ep.x;
            float we = __int_as_float(ep.y);
            float4 e = el4[si];
            float ax = __expf(we * lrelu(e.x + ern.x) - mx.x) * inv.x;
            float ay = __expf(we * lrelu(e.y + ern.y) - mx.y) * inv.y;
            float az = __expf(we * lrelu(e.z + ern.z) - mx.z) * inv.z;
            float aw = __expf(we * lrelu(e.w + ern.w) - mx.w) * inv.w;
            float wgt = head == 0 ? ax : (head == 1 ? ay : (head == 2 ? az : aw));
            u32 p = fth2[(size_t)si * 64 + lane];
            f16x2 hp = *(const f16x2*)&p;
            acc0 += wgt * (float)hp.x;
            acc1 += wgt * (float)hp.y;
        }
    }
    f16x2 hv;
    hv.x = (f16)fmaxf(acc0, 0.f);
    hv.y = (f16)fmaxf(acc1, 0.f);
    *(f16x2*)op = hv;
}

// ---------------- launch ----------------

extern "C" void kernel_launch(void* const* d_in, const int* in_sizes, int n_in,
                              void* d_out, int out_size, void* d_ws, size_t ws_size,
                              hipStream_t stream) {
    const float* features = (const float*)d_in[0];
    const int* src = (const int*)d_in[1];
    const int* dst = (const int*)d_in[2];
    const float* w = (const float*)d_in[3];
    const float* W1 = (const float*)d_in[4];
    const float* al1 = (const float*)d_in[5];
    const float* ar1 = (const float*)d_in[6];
    const float* W2 = (const float*)d_in[7];
    const float* al2 = (const float*)d_in[8];
    const float* ar2 = (const float*)d_in[9];
    const float* Wout = (const float*)d_in[10];
    const float* bout = (const float*)d_in[11];
    float* out = (float*)d_out;

    int N = in_sizes[0] / 256;           // 50000
    int E = in_sizes[1];                 // 400000
    int Mpad = ((N + 127) / 128) * 128;  // 50048

    char* ws = (char*)d_ws;
    size_t off = 0;
    auto alloc = [&](size_t bytes) -> void* {
        void* p = ws + off;
        off = (off + bytes + 255) & ~(size_t)255;
        return p;
    };
    size_t Nr = ((size_t)N * 4 + 255) & ~(size_t)255;
    int* cnt = (int*)alloc(2 * Nr + 256);            // cnt + fill + ctr, single memset
    int* fill = (int*)((char*)cnt + Nr);
    int* ctr = (int*)((char*)cnt + 2 * Nr);
    int* start = (int*)alloc((size_t)N * 4);
    int2* edge_s = (int2*)alloc((size_t)E * 8);
    u16* fth = (u16*)alloc((size_t)Mpad * 128 * 2);   // fp16 node features (per layer)
    float* el = (float*)alloc((size_t)N * 4 * 4);
    float* er = (float*)alloc((size_t)N * 4 * 4);
    u16* xcat = (u16*)alloc((size_t)Mpad * 256 * 2);  // concat(x1,x2) fp16
    u16* b1 = (u16*)alloc((size_t)18432 * 4);         // 144-col panel, K=256
    u16* b2 = (u16*)alloc((size_t)9216 * 4);          // 144-col panel, K=128
    u16* b3 = (u16*)alloc((size_t)16384 * 4);         // 128-col panel, K=256
    (void)ws_size; (void)n_in; (void)out_size;

    hipMemsetAsync(cnt, 0, 2 * Nr + 256, stream);

    int eb = (E + 255) / 256;
    int nb = (N + 255) / 256;
    int wb = (N + 3) / 4;
    int gb = Mpad / 64;   // 782 blocks (64-row tiles)

    // CSR-ish build + weight panels
    histcast_k<<<eb, 256, 0, stream>>>(dst, cnt, E, W1, al1, ar1, b1,
                                       W2, al2, ar2, b2, Wout, b3);
    assign_k<<<nb, 256, 0, stream>>>(cnt, start, ctr, N);
    scatter_k<<<eb, 256, 0, stream>>>(src, dst, w, start, fill, edge_s, E);

    // layer 1: fth = fp16(features @ W1), el/er fused as extra B columns
    gemm_h_k<9, 8><<<gb, 256, 0, stream>>>(features, 0, 256, b1, nullptr,
                                           nullptr, fth, el, er, N);
    agg_k<<<wb, 256, 0, stream>>>((const u32*)fth, (const float4*)el, (const float4*)er,
                                  edge_s, start, cnt, xcat, 0, N);

    // layer 2: fth = fp16(x1 @ W2)
    gemm_h_k<9, 4><<<gb, 256, 0, stream>>>(xcat, 1, 256, b2, nullptr,
                                           nullptr, fth, el, er, N);
    agg_k<<<wb, 256, 0, stream>>>((const u32*)fth, (const float4*)el, (const float4*)er,
                                  edge_s, start, cnt, xcat, 128, N);

    // output GEMM: out = xcat @ Wout + bout
    gemm_h_k<8, 8><<<gb, 256, 0, stream>>>(xcat, 1, 256, b3, bout,
                                           out, nullptr, nullptr, nullptr, N);
}